// Round 1
// baseline (68659.943 us; speedup 1.0000x reference)
//
#include <hip/hip_runtime.h>
#include <hip/hip_fp16.h>

#define NB   256
#define TT   1024
#define II   64
#define HH1  128
#define GG1  512
#define HH2  64
#define GG2  256

typedef _Float16 f16;
typedef _Float16 f16x2 __attribute__((ext_vector_type(2)));

__device__ __forceinline__ float rcp_fast(float x){
    float r; asm("v_rcp_f32 %0, %1" : "=v"(r) : "v"(x)); return r;
}
__device__ __forceinline__ float sigm(float x){
    return rcp_fast(1.0f + __expf(-x));
}
__device__ __forceinline__ float tanh_f(float x){
    x = fminf(10.0f, fmaxf(-10.0f, x));
    float e = __expf(2.0f * x);
    return (e - 1.0f) * rcp_fast(e + 1.0f);
}
__device__ __forceinline__ f16x2 pack2(float a, float b){
    f16x2 r; r.x = (f16)a; r.y = (f16)b; return r;
}

__launch_bounds__(512, 2)
__global__ void lstm_fused(const float* __restrict__ x,
                           const float* __restrict__ Wih1, const float* __restrict__ Whh1,
                           const float* __restrict__ bih1, const float* __restrict__ bhh1,
                           const float* __restrict__ Wih2, const float* __restrict__ Whh2,
                           const float* __restrict__ bih2, const float* __restrict__ bhh2,
                           const float* __restrict__ W1,   const float* __restrict__ b1,
                           const float* __restrict__ W2,   const float* __restrict__ b2,
                           float* __restrict__ out)
{
    __shared__ __align__(16) float xs[II];     // x_t (fp32)
    __shared__ __align__(16) float h1s[HH1];   // h1_t (fp32)
    __shared__ __align__(16) float h2s[HH2];   // h2_{t-1} (fp32)
    __shared__ __align__(16) float g1[GG1];    // layer-1 gate preacts
    __shared__ __align__(16) float p2[2*GG2];  // layer-2 partial dots
    __shared__ __align__(16) float head[32];

    const int j = threadIdx.x;          // 0..511
    const int b = blockIdx.x;           // batch element

    // ---------- one-time: weights -> f16 pairs in VGPRs ----------
    // Layer 1: thread j owns gate-row j.
    f16x2 wih[32];
    {
        const float4* wr = (const float4*)(Wih1 + j*II);
        #pragma unroll
        for (int q = 0; q < 16; ++q){
            float4 v = wr[q];
            wih[2*q]   = pack2(v.x, v.y);
            wih[2*q+1] = pack2(v.z, v.w);
        }
    }
    f16x2 whh[64];
    {
        const float4* hr = (const float4*)(Whh1 + j*HH1);
        #pragma unroll
        for (int q = 0; q < 32; ++q){
            float4 v = hr[q];
            whh[2*q]   = pack2(v.x, v.y);
            whh[2*q+1] = pack2(v.z, v.w);
        }
    }
    // Layer 2: gate-row g split in half over K (=[h1(128);h2(64)]).
    const int g    = j & 255;
    const int half = j >> 8;           // 0: K 0..95, 1: K 96..191
    f16x2 w2[48];
    if (half == 0){
        const float4* p = (const float4*)(Wih2 + g*HH1);
        #pragma unroll
        for (int q = 0; q < 24; ++q){
            float4 v = p[q];
            w2[2*q]   = pack2(v.x, v.y);
            w2[2*q+1] = pack2(v.z, v.w);
        }
    } else {
        const float4* p = (const float4*)(Wih2 + g*HH1 + 96);
        #pragma unroll
        for (int q = 0; q < 8; ++q){
            float4 v = p[q];
            w2[2*q]   = pack2(v.x, v.y);
            w2[2*q+1] = pack2(v.z, v.w);
        }
        const float4* ph = (const float4*)(Whh2 + g*HH2);
        #pragma unroll
        for (int q = 0; q < 16; ++q){
            float4 v = ph[q];
            w2[16+2*q]   = pack2(v.x, v.y);
            w2[16+2*q+1] = pack2(v.z, v.w);
        }
    }

    const float bias1 = bih1[j] + bhh1[j];
    float b2i = 0.f, b2f = 0.f, b2g = 0.f, b2o = 0.f;
    if (j < HH2){
        b2i = bih2[j]         + bhh2[j];
        b2f = bih2[HH2+j]     + bhh2[HH2+j];
        b2g = bih2[2*HH2+j]   + bhh2[2*HH2+j];
        b2o = bih2[3*HH2+j]   + bhh2[3*HH2+j];
    }

    const float* xb = x + (size_t)b * TT * II;
    if (j < HH1) h1s[j] = 0.0f;
    if (j < HH2) h2s[j] = 0.0f;
    if (j < II)  xs[j]  = xb[j];
    float c1 = 0.0f, c2 = 0.0f;
    __syncthreads();

    for (int t = 0; t < TT; ++t){
        // wave 2 prefetches next x_t (latency hidden under the dots)
        float xn = 0.0f;
        if (j >= 128 && j < 192){
            int tn = (t+1 < TT) ? (t+1) : (TT-1);
            xn = xb[tn*II + (j-128)];
        }

        // ---- P0: layer-1 gate preact for gate j; wave0(<64) also finishes
        //          layer-2 step t-1 from p2 ----
        float acc = bias1;
        const float4* xs4 = (const float4*)xs;
        #pragma unroll
        for (int q = 0; q < 16; ++q){
            float4 v = xs4[q];
            acc = fmaf((float)wih[2*q].x,   v.x, acc);
            acc = fmaf((float)wih[2*q].y,   v.y, acc);
            acc = fmaf((float)wih[2*q+1].x, v.z, acc);
            acc = fmaf((float)wih[2*q+1].y, v.w, acc);
        }
        const float4* h1s4 = (const float4*)h1s;
        #pragma unroll
        for (int q = 0; q < 32; ++q){
            float4 v = h1s4[q];
            acc = fmaf((float)whh[2*q].x,   v.x, acc);
            acc = fmaf((float)whh[2*q].y,   v.y, acc);
            acc = fmaf((float)whh[2*q+1].x, v.z, acc);
            acc = fmaf((float)whh[2*q+1].y, v.w, acc);
        }

        if (t > 0 && j < HH2){
            float vi = p2[j]        + p2[GG2+j]         + b2i;
            float vf = p2[HH2+j]    + p2[GG2+HH2+j]     + b2f;
            float vg = p2[2*HH2+j]  + p2[GG2+2*HH2+j]   + b2g;
            float vo = p2[3*HH2+j]  + p2[GG2+3*HH2+j]   + b2o;
            float ii = sigm(vi), ff = sigm(vf), gg = tanh_f(vg), oo = sigm(vo);
            c2 = ff*c2 + ii*gg;
            h2s[j] = oo * tanh_f(c2);
        }
        g1[j] = acc;
        __syncthreads();

        // ---- P1: layer-1 activations, update h1/c1 (threads 0..127) ----
        if (j < HH1){
            float ii = sigm(g1[j]);
            float ff = sigm(g1[HH1+j]);
            float gg = tanh_f(g1[2*HH1+j]);
            float oo = sigm(g1[3*HH1+j]);
            c1 = ff*c1 + ii*gg;
            h1s[j] = oo * tanh_f(c1);
        }
        __syncthreads();

        // ---- P2: layer-2 partial dots (uses h1_t and h2_{t-1}) ----
        float acc2 = 0.0f;
        if (half == 0){
            #pragma unroll
            for (int q = 0; q < 24; ++q){
                float4 v = h1s4[q];
                acc2 = fmaf((float)w2[2*q].x,   v.x, acc2);
                acc2 = fmaf((float)w2[2*q].y,   v.y, acc2);
                acc2 = fmaf((float)w2[2*q+1].x, v.z, acc2);
                acc2 = fmaf((float)w2[2*q+1].y, v.w, acc2);
            }
        } else {
            #pragma unroll
            for (int q = 0; q < 8; ++q){
                float4 v = h1s4[24+q];
                acc2 = fmaf((float)w2[2*q].x,   v.x, acc2);
                acc2 = fmaf((float)w2[2*q].y,   v.y, acc2);
                acc2 = fmaf((float)w2[2*q+1].x, v.z, acc2);
                acc2 = fmaf((float)w2[2*q+1].y, v.w, acc2);
            }
            const float4* h2s4 = (const float4*)h2s;
            #pragma unroll
            for (int q = 0; q < 16; ++q){
                float4 v = h2s4[q];
                acc2 = fmaf((float)w2[16+2*q].x,   v.x, acc2);
                acc2 = fmaf((float)w2[16+2*q].y,   v.y, acc2);
                acc2 = fmaf((float)w2[16+2*q+1].x, v.z, acc2);
                acc2 = fmaf((float)w2[16+2*q+1].y, v.w, acc2);
            }
        }
        p2[j] = acc2;
        if (j >= 128 && j < 192) xs[j-128] = xn;   // publish x_{t+1}
        __syncthreads();
    }

    // ---- finish layer-2 step T-1 ----
    if (j < HH2){
        float vi = p2[j]        + p2[GG2+j]         + b2i;
        float vf = p2[HH2+j]    + p2[GG2+HH2+j]     + b2f;
        float vg = p2[2*HH2+j]  + p2[GG2+2*HH2+j]   + b2g;
        float vo = p2[3*HH2+j]  + p2[GG2+3*HH2+j]   + b2o;
        float ii = sigm(vi), ff = sigm(vf), gg = tanh_f(vg), oo = sigm(vo);
        c2 = ff*c2 + ii*gg;
        h2s[j] = oo * tanh_f(c2);
    }
    __syncthreads();

    // ---- MLP head ----
    if (j < 32){
        float a = b1[j];
        const float* w = W1 + j*HH2;
        #pragma unroll
        for (int k = 0; k < HH2; ++k) a = fmaf(w[k], h2s[k], a);
        head[j] = sigm(a);
    }
    __syncthreads();
    if (j == 0){
        float a = b2[0];
        #pragma unroll
        for (int k = 0; k < 32; ++k) a = fmaf(W2[k], head[k], a);
        out[b] = sigm(a);
    }
}

extern "C" void kernel_launch(void* const* d_in, const int* in_sizes, int n_in,
                              void* d_out, int out_size, void* d_ws, size_t ws_size,
                              hipStream_t stream)
{
    (void)in_sizes; (void)n_in; (void)d_ws; (void)ws_size; (void)out_size;
    lstm_fused<<<NB, 512, 0, stream>>>(
        (const float*)d_in[0],
        (const float*)d_in[1], (const float*)d_in[2],
        (const float*)d_in[3], (const float*)d_in[4],
        (const float*)d_in[5], (const float*)d_in[6],
        (const float*)d_in[7], (const float*)d_in[8],
        (const float*)d_in[9], (const float*)d_in[10],
        (const float*)d_in[11], (const float*)d_in[12],
        (float*)d_out);
}

// Round 2
// 1461.757 us; speedup vs baseline: 46.9708x; 46.9708x over previous
//
#include <hip/hip_runtime.h>
#include <hip/hip_fp16.h>

#define NB   256
#define TT   1024
#define II   64
#define HH1  128
#define GG1  512
#define HH2  64
#define GG2  256

typedef _Float16 f16;
typedef _Float16 f16x2 __attribute__((ext_vector_type(2)));

union F4 { float4 f; f16x2 h[4]; };

__device__ __forceinline__ float rcp_fast(float x){
    float r; asm("v_rcp_f32 %0, %1" : "=v"(r) : "v"(x)); return r;
}
__device__ __forceinline__ float sigm(float x){
    return rcp_fast(1.0f + __expf(-x));
}
__device__ __forceinline__ float tanh_f(float x){
    x = fminf(10.0f, fmaxf(-10.0f, x));
    float e = __expf(2.0f * x);
    return (e - 1.0f) * rcp_fast(e + 1.0f);
}
__device__ __forceinline__ f16x2 pack2(float a, float b){
    f16x2 r; r.x = (f16)a; r.y = (f16)b; return r;
}
__device__ __forceinline__ float dot2(f16x2 a, f16x2 b, float c){
#if __has_builtin(__builtin_amdgcn_fdot2)
    return __builtin_amdgcn_fdot2(a, b, c, false);
#else
    return fmaf((float)a.x, (float)b.x, fmaf((float)a.y, (float)b.y, c));
#endif
}

__launch_bounds__(512, 1)
__global__ void lstm_fused(const float* __restrict__ x,
                           const float* __restrict__ Wih1, const float* __restrict__ Whh1,
                           const float* __restrict__ bih1, const float* __restrict__ bhh1,
                           const float* __restrict__ Wih2, const float* __restrict__ Whh2,
                           const float* __restrict__ bih2, const float* __restrict__ bhh2,
                           const float* __restrict__ W1,   const float* __restrict__ b1,
                           const float* __restrict__ W2,   const float* __restrict__ b2,
                           float* __restrict__ out)
{
    __shared__ __align__(16) f16   xs[II];      // x_t  (f16)
    __shared__ __align__(16) f16   h1h[HH1];    // h1_t (f16)
    __shared__ __align__(16) f16   h2h[HH2];    // h2_{t-1} (f16)
    __shared__ __align__(16) float g1[GG1];     // layer-1 gate preacts (fp32)
    __shared__ __align__(16) float p2[2*GG2];   // layer-2 partial dots (fp32)
    __shared__ __align__(16) float head[32];

    const int j = threadIdx.x;          // 0..511
    const int b = blockIdx.x;           // batch element

    // ---------- one-time: weights -> f16 pairs in VGPRs ----------
    f16x2 wih[32];                       // layer1 Wih row j (64 elems)
    {
        const float4* wr = (const float4*)(Wih1 + j*II);
        #pragma unroll
        for (int q = 0; q < 16; ++q){
            float4 v = wr[q];
            wih[2*q]   = pack2(v.x, v.y);
            wih[2*q+1] = pack2(v.z, v.w);
        }
    }
    f16x2 whh[64];                       // layer1 Whh row j (128 elems)
    {
        const float4* hr = (const float4*)(Whh1 + j*HH1);
        #pragma unroll
        for (int q = 0; q < 32; ++q){
            float4 v = hr[q];
            whh[2*q]   = pack2(v.x, v.y);
            whh[2*q+1] = pack2(v.z, v.w);
        }
    }
    // Layer 2: gate-row g, K split in half over [h1(128); h2(64)].
    const int g    = j & 255;
    const int half = j >> 8;             // 0: K 0..95  |  1: K 96..191
    f16x2 w2[48];
    if (half == 0){
        const float4* p = (const float4*)(Wih2 + g*HH1);
        #pragma unroll
        for (int q = 0; q < 24; ++q){
            float4 v = p[q];
            w2[2*q]   = pack2(v.x, v.y);
            w2[2*q+1] = pack2(v.z, v.w);
        }
    } else {
        const float4* p = (const float4*)(Wih2 + g*HH1 + 96);
        #pragma unroll
        for (int q = 0; q < 8; ++q){
            float4 v = p[q];
            w2[2*q]   = pack2(v.x, v.y);
            w2[2*q+1] = pack2(v.z, v.w);
        }
        const float4* ph = (const float4*)(Whh2 + g*HH2);
        #pragma unroll
        for (int q = 0; q < 16; ++q){
            float4 v = ph[q];
            w2[16+2*q]   = pack2(v.x, v.y);
            w2[16+2*q+1] = pack2(v.z, v.w);
        }
    }

    const float bias1 = bih1[j] + bhh1[j];
    float b2i = 0.f, b2f = 0.f, b2g = 0.f, b2o = 0.f;
    if (j < HH2){
        b2i = bih2[j]         + bhh2[j];
        b2f = bih2[HH2+j]     + bhh2[HH2+j];
        b2g = bih2[2*HH2+j]   + bhh2[2*HH2+j];
        b2o = bih2[3*HH2+j]   + bhh2[3*HH2+j];
    }

    const float* xb = x + (size_t)b * TT * II;
    if (j < HH1) h1h[j] = (f16)0.0f;
    if (j < HH2) h2h[j] = (f16)0.0f;
    if (j < II)  xs[j]  = (f16)xb[j];
    float c1 = 0.0f, c2 = 0.0f;
    __syncthreads();

    const float4* xf4  = (const float4*)xs;    // 8  x float4 (8 f16 each)
    const float4* h1f4 = (const float4*)h1h;   // 16 x float4
    const float4* h2f4 = (const float4*)h2h;   // 8  x float4

    for (int t = 0; t < TT; ++t){
        // wave 2 prefetches next x_t (latency hidden under the dots)
        float xn = 0.0f;
        if (j >= 128 && j < 192){
            int tn = (t+1 < TT) ? (t+1) : (TT-1);
            xn = xb[tn*II + (j-128)];
        }

        // ---- P0: layer-1 gate preact for gate j (96 dot2);
        //          threads <64 also finish layer-2 step t-1 from p2 ----
        float a0 = bias1, a1 = 0.f, a2 = 0.f, a3 = 0.f;
        #pragma unroll
        for (int q = 0; q < 8; ++q){
            F4 u; u.f = xf4[q];
            a0 = dot2(wih[4*q+0], u.h[0], a0);
            a1 = dot2(wih[4*q+1], u.h[1], a1);
            a2 = dot2(wih[4*q+2], u.h[2], a2);
            a3 = dot2(wih[4*q+3], u.h[3], a3);
        }
        #pragma unroll
        for (int q = 0; q < 16; ++q){
            F4 u; u.f = h1f4[q];
            a0 = dot2(whh[4*q+0], u.h[0], a0);
            a1 = dot2(whh[4*q+1], u.h[1], a1);
            a2 = dot2(whh[4*q+2], u.h[2], a2);
            a3 = dot2(whh[4*q+3], u.h[3], a3);
        }

        if (t > 0 && j < HH2){
            float vi = p2[j]        + p2[GG2+j]         + b2i;
            float vf = p2[HH2+j]    + p2[GG2+HH2+j]     + b2f;
            float vg = p2[2*HH2+j]  + p2[GG2+2*HH2+j]   + b2g;
            float vo = p2[3*HH2+j]  + p2[GG2+3*HH2+j]   + b2o;
            float ii = sigm(vi), ff = sigm(vf), gg = tanh_f(vg), oo = sigm(vo);
            c2 = ff*c2 + ii*gg;
            h2h[j] = (f16)(oo * tanh_f(c2));
        }
        g1[j] = (a0 + a1) + (a2 + a3);
        __syncthreads();

        // ---- P1: layer-1 activations, update h1/c1 (threads 0..127) ----
        if (j < HH1){
            float ii = sigm(g1[j]);
            float ff = sigm(g1[HH1+j]);
            float gg = tanh_f(g1[2*HH1+j]);
            float oo = sigm(g1[3*HH1+j]);
            c1 = ff*c1 + ii*gg;
            h1h[j] = (f16)(oo * tanh_f(c1));
        }
        __syncthreads();

        // ---- P2: layer-2 partial dots (uses h1_t and h2_{t-1}) ----
        float s0 = 0.f, s1 = 0.f, s2 = 0.f, s3 = 0.f;
        if (half == 0){
            #pragma unroll
            for (int q = 0; q < 12; ++q){
                F4 u; u.f = h1f4[q];
                s0 = dot2(w2[4*q+0], u.h[0], s0);
                s1 = dot2(w2[4*q+1], u.h[1], s1);
                s2 = dot2(w2[4*q+2], u.h[2], s2);
                s3 = dot2(w2[4*q+3], u.h[3], s3);
            }
        } else {
            #pragma unroll
            for (int q = 0; q < 4; ++q){
                F4 u; u.f = h1f4[12+q];
                s0 = dot2(w2[4*q+0], u.h[0], s0);
                s1 = dot2(w2[4*q+1], u.h[1], s1);
                s2 = dot2(w2[4*q+2], u.h[2], s2);
                s3 = dot2(w2[4*q+3], u.h[3], s3);
            }
            #pragma unroll
            for (int q = 0; q < 8; ++q){
                F4 u; u.f = h2f4[q];
                s0 = dot2(w2[16+4*q+0], u.h[0], s0);
                s1 = dot2(w2[16+4*q+1], u.h[1], s1);
                s2 = dot2(w2[16+4*q+2], u.h[2], s2);
                s3 = dot2(w2[16+4*q+3], u.h[3], s3);
            }
        }
        p2[j] = (s0 + s1) + (s2 + s3);
        if (j >= 128 && j < 192) xs[j-128] = (f16)xn;   // publish x_{t+1}
        __syncthreads();
    }

    // ---- finish layer-2 step T-1 ----
    if (j < HH2){
        float vi = p2[j]        + p2[GG2+j]         + b2i;
        float vf = p2[HH2+j]    + p2[GG2+HH2+j]     + b2f;
        float vg = p2[2*HH2+j]  + p2[GG2+2*HH2+j]   + b2g;
        float vo = p2[3*HH2+j]  + p2[GG2+3*HH2+j]   + b2o;
        float ii = sigm(vi), ff = sigm(vf), gg = tanh_f(vg), oo = sigm(vo);
        c2 = ff*c2 + ii*gg;
        h2h[j] = (f16)(oo * tanh_f(c2));
    }
    __syncthreads();

    // ---- MLP head ----
    if (j < 32){
        float a = b1[j];
        const float* w = W1 + j*HH2;
        #pragma unroll
        for (int k = 0; k < HH2; ++k) a = fmaf(w[k], (float)h2h[k], a);
        head[j] = sigm(a);
    }
    __syncthreads();
    if (j == 0){
        float a = b2[0];
        #pragma unroll
        for (int k = 0; k < 32; ++k) a = fmaf(W2[k], head[k], a);
        out[b] = sigm(a);
    }
}

extern "C" void kernel_launch(void* const* d_in, const int* in_sizes, int n_in,
                              void* d_out, int out_size, void* d_ws, size_t ws_size,
                              hipStream_t stream)
{
    (void)in_sizes; (void)n_in; (void)d_ws; (void)ws_size; (void)out_size;
    lstm_fused<<<NB, 512, 0, stream>>>(
        (const float*)d_in[0],
        (const float*)d_in[1], (const float*)d_in[2],
        (const float*)d_in[3], (const float*)d_in[4],
        (const float*)d_in[5], (const float*)d_in[6],
        (const float*)d_in[7], (const float*)d_in[8],
        (const float*)d_in[9], (const float*)d_in[10],
        (const float*)d_in[11], (const float*)d_in[12],
        (float*)d_out);
}